// Round 7
// baseline (306.392 us; speedup 1.0000x reference)
//
#include <hip/hip_runtime.h>
#include <hip/hip_bf16.h>

#define NMOL    2048
#define MOLSIZE 100
#define TRI     4950                  // MOLSIZE*(MOLSIZE-1)/2 upper-triangle pairs
#define NCH     78                    // ceil(TRI/64) wave-sized chunks per molecule
#define CUTOFF2 9.0f                  // OUTERCUTOFF^2

// ws layout (int32) — total (4*NMOL+2)*4 = 32,776 bytes (Round-1-proven footprint):
// [0        .. NMOL)       per-molecule real-atom count
// [NMOL     .. 2*NMOL)     per-molecule selected-pair count
// [2*NMOL   .. 3*NMOL)     exclusive atom base
// [3*NMOL   .. 4*NMOL)     exclusive pair base
// [4*NMOL], [4*NMOL+1]     n_real, npairs totals

// row i of the strict upper triangle holds pairs (i, i+1..99): count 99-i.
// S(i) = 99*i - i*(i-1)/2 = index of first pair in row i.
__device__ __forceinline__ int tri_row_start(int i) {
    return 99 * i - (i * (i - 1)) / 2;
}
__device__ __forceinline__ void tri_decode(int p, int& i, int& j) {
    const int disc = 39601 - 8 * p;                    // (199)^2 - 8p, exact in int
    const float q = sqrtf((float)disc);
    int ii = (int)((199.0f - q) * 0.5f);
    if (ii < 0) ii = 0;
    if (ii > 98) ii = 98;
    while (tri_row_start(ii + 1) <= p) ++ii;           // corrects any sqrt rounding
    while (tri_row_start(ii) > p) --ii;
    i = ii;
    j = ii + 1 + (p - tri_row_start(ii));
}

__global__ __launch_bounds__(256) void k_count(const int* __restrict__ species,
                                               const float* __restrict__ coords,
                                               float* __restrict__ out,
                                               int* __restrict__ ws) {
    const int m = blockIdx.x;
    const int tid = threadIdx.x;
    const int lane = tid & 63, wv = tid >> 6;

    __shared__ float sc[MOLSIZE * 3];
    __shared__ int   ssp[MOLSIZE];
    __shared__ int   s_nb[4], s_hv[4], s_hy[4], s_pc[4];

    for (int t = tid; t < MOLSIZE * 3; t += 256)
        sc[t] = coords[(size_t)m * (MOLSIZE * 3) + t];
    for (int t = tid; t < MOLSIZE; t += 256)
        ssp[t] = species[m * MOLSIZE + t];
    __syncthreads();

    // atom-level counts (tid 0..99 carry flags)
    const int sp = (tid < MOLSIZE) ? ssp[tid] : 0;
    unsigned long long bnb = __ballot(sp > 0);
    unsigned long long bhv = __ballot(sp > 1);
    unsigned long long bhy = __ballot(sp == 1);
    if (lane == 0) { s_nb[wv] = __popcll(bnb); s_hv[wv] = __popcll(bhv); s_hy[wv] = __popcll(bhy); }

    // per-wave pair counting over wave-sized triangle chunks
    int wcount = 0;
    for (int c = wv; c < NCH; c += 4) {
        const int p = c * 64 + lane;
        bool flag = false;
        if (p < TRI) {
            int i, j;
            tri_decode(p, i, j);
            if (ssp[i] > 0 && ssp[j] > 0) {
                const float dx = __fsub_rn(sc[j * 3 + 0], sc[i * 3 + 0]);
                const float dy = __fsub_rn(sc[j * 3 + 1], sc[i * 3 + 1]);
                const float dz = __fsub_rn(sc[j * 3 + 2], sc[i * 3 + 2]);
                const float d2 = __fadd_rn(__fadd_rn(__fmul_rn(dx, dx), __fmul_rn(dy, dy)),
                                           __fmul_rn(dz, dz));
                flag = d2 < CUTOFF2;
            }
        }
        wcount += __popcll(__ballot(flag));
    }
    if (lane == 0) s_pc[wv] = wcount;
    __syncthreads();

    if (tid == 0) {
        ws[m]        = s_nb[0] + s_nb[1] + s_nb[2] + s_nb[3];
        ws[NMOL + m] = s_pc[0] + s_pc[1] + s_pc[2] + s_pc[3];
        out[2 + m]        = (float)(s_hv[0] + s_hv[1] + s_hv[2] + s_hv[3]);  // nHeavy
        out[2 + NMOL + m] = (float)(s_hy[0] + s_hy[1] + s_hy[2] + s_hy[3]);  // nHydro
        if (m == 0) { out[0] = (float)NMOL; out[1] = (float)MOLSIZE; }
    }
}

__global__ __launch_bounds__(256) void k_scan(int* __restrict__ ws) {
    const int tid = threadIdx.x, lane = tid & 63, wv = tid >> 6;
    __shared__ int wsum[4];
    for (int which = 0; which < 2; ++which) {
        const int* src = ws + which * NMOL;
        int*       dst = ws + (2 + which) * NMOL;
        int run = 0;
        for (int base = 0; base < NMOL; base += 256) {
            const int v = src[base + tid];
            int x = v;
            for (int o = 1; o < 64; o <<= 1) { int y = __shfl_up(x, o); if (lane >= o) x += y; }
            if (lane == 63) wsum[wv] = x;
            __syncthreads();
            int add = 0;
            for (int w = 0; w < wv; ++w) add += wsum[w];
            const int tot = wsum[0] + wsum[1] + wsum[2] + wsum[3];
            dst[base + tid] = run + add + (x - v);   // exclusive
            run += tot;
            __syncthreads();
        }
        if (tid == 0) ws[4 * NMOL + which] = run;
    }
}

__global__ __launch_bounds__(256) void k_write(const int* __restrict__ species,
                                               const float* __restrict__ coords,
                                               const float* __restrict__ lcf_p,
                                               float* __restrict__ out,
                                               const int* __restrict__ ws) {
    const int m = blockIdx.x;
    const int tid = threadIdx.x;
    const int lane = tid & 63, wv = tid >> 6;

    __shared__ float sc[MOLSIZE * 3];
    __shared__ int   ssp[MOLSIZE];
    __shared__ int   srank[MOLSIZE];
    __shared__ unsigned long long chBal[NCH];   // per-chunk flag ballots
    __shared__ int   chOff[NCH];                // exclusive scan of chunk counts
    __shared__ int   wcnt[4];

    for (int t = tid; t < MOLSIZE * 3; t += 256)
        sc[t] = coords[(size_t)m * (MOLSIZE * 3) + t];
    for (int t = tid; t < MOLSIZE; t += 256)
        ssp[t] = species[m * MOLSIZE + t];
    __syncthreads();

    const int atomBase = ws[2 * NMOL + m];
    const int pairBase = ws[3 * NMOL + m];
    const int nReal    = ws[4 * NMOL];
    const int nPairs   = ws[4 * NMOL + 1];
    const float lcf    = lcf_p[0];

    // output region offsets (float32, concatenated in reference return order)
    const size_t off_Z      = 2 + 2 * (size_t)NMOL;          // 4098
    const size_t off_maskd  = off_Z + (size_t)nReal;
    const size_t off_amolid = off_Z + 2 * (size_t)nReal;
    const size_t off_mask   = off_Z + 3 * (size_t)nReal;
    const size_t off_pmolid = off_mask + 1 * (size_t)nPairs;
    const size_t off_ni     = off_mask + 2 * (size_t)nPairs;
    const size_t off_nj     = off_mask + 3 * (size_t)nPairs;
    const size_t off_idxi   = off_mask + 4 * (size_t)nPairs;
    const size_t off_idxj   = off_mask + 5 * (size_t)nPairs;
    const size_t off_xij    = off_mask + 6 * (size_t)nPairs;
    const size_t off_rij    = off_mask + 9 * (size_t)nPairs;

    // ---- atom ballot (no LDS deps) ----
    const int aflag = (tid < MOLSIZE) && (ssp[tid] > 0);
    const unsigned long long ab = __ballot(aflag);
    const int aLanePre = __popcll(ab & ((1ull << lane) - 1ull));
    if (lane == 0) wcnt[wv] = __popcll(ab);

    // ---- pass A: per-chunk pair-flag ballots into LDS ----
    for (int c = wv; c < NCH; c += 4) {
        const int p = c * 64 + lane;
        bool flag = false;
        if (p < TRI) {
            int i, j;
            tri_decode(p, i, j);
            if (ssp[i] > 0 && ssp[j] > 0) {
                const float dx = __fsub_rn(sc[j * 3 + 0], sc[i * 3 + 0]);
                const float dy = __fsub_rn(sc[j * 3 + 1], sc[i * 3 + 1]);
                const float dz = __fsub_rn(sc[j * 3 + 2], sc[i * 3 + 2]);
                const float d2 = __fadd_rn(__fadd_rn(__fmul_rn(dx, dx), __fmul_rn(dy, dy)),
                                           __fmul_rn(dz, dz));
                flag = d2 < CUTOFF2;
            }
        }
        const unsigned long long bb = __ballot(flag);
        if (lane == 0) chBal[c] = bb;
    }
    __syncthreads();   // wcnt + chBal ready

    // ---- atom writes (waves 0-1) in parallel with chunk-offset scan (tid 255) ----
    {
        int wbase = 0;
        for (int w = 0; w < wv; ++w) wbase += wcnt[w];
        if (aflag) {
            const int r = wbase + aLanePre;
            srank[tid] = r;
            const size_t g = (size_t)atomBase + r;
            out[off_Z + g]      = (float)ssp[tid];
            out[off_maskd + g]  = (float)(m * (MOLSIZE * MOLSIZE) + tid * (MOLSIZE + 1));
            out[off_amolid + g] = (float)m;
        }
        if (tid == 255) {                   // idle lane: serial exclusive scan of 78 counts
            int run = 0;
            for (int c = 0; c < NCH; ++c) { chOff[c] = run; run += __popcll(chBal[c]); }
        }
    }
    __syncthreads();   // srank + chOff ready

    // ---- pass B: flagged lanes recompute geometry and write; zero barriers ----
    for (int c = wv; c < NCH; c += 4) {
        const unsigned long long bb = chBal[c];
        if ((bb >> lane) & 1ull) {
            const int p = c * 64 + lane;
            int i, j;
            tri_decode(p, i, j);
            const float dx = __fsub_rn(sc[j * 3 + 0], sc[i * 3 + 0]);
            const float dy = __fsub_rn(sc[j * 3 + 1], sc[i * 3 + 1]);
            const float dz = __fsub_rn(sc[j * 3 + 2], sc[i * 3 + 2]);
            const float d2 = __fadd_rn(__fadd_rn(__fmul_rn(dx, dx), __fmul_rn(dy, dy)),
                                       __fmul_rn(dz, dz));
            const int r = pairBase + chOff[c] + __popcll(bb & ((1ull << lane) - 1ull));
            const float pd = __fmul_rn(d2, d2);              // square of dist^2 (faithful)
            out[off_mask + r]   = (float)((m * MOLSIZE + i) * MOLSIZE + j);
            out[off_pmolid + r] = (float)m;
            out[off_ni + r]     = (float)ssp[i];
            out[off_nj + r]     = (float)ssp[j];
            out[off_idxi + r]   = (float)(atomBase + srank[i]);
            out[off_idxj + r]   = (float)(atomBase + srank[j]);
            out[off_xij + 3 * (size_t)r + 0] = __fdiv_rn(dx, pd);
            out[off_xij + 3 * (size_t)r + 1] = __fdiv_rn(dy, pd);
            out[off_xij + 3 * (size_t)r + 2] = __fdiv_rn(dz, pd);
            out[off_rij + r]    = __fmul_rn(pd, lcf);
        }
    }
}

extern "C" void kernel_launch(void* const* d_in, const int* in_sizes, int n_in,
                              void* d_out, int out_size, void* d_ws, size_t ws_size,
                              hipStream_t stream) {
    const int*   species = (const int*)d_in[0];
    const float* coords  = (const float*)d_in[1];
    // d_in[2] = tore: only feeds the closed-shell assert (always passes) — unused
    const float* lcf     = (const float*)d_in[3];
    float*       out     = (float*)d_out;
    int*         ws      = (int*)d_ws;

    k_count<<<dim3(NMOL), dim3(256), 0, stream>>>(species, coords, out, ws);
    k_scan <<<dim3(1),    dim3(256), 0, stream>>>(ws);
    k_write<<<dim3(NMOL), dim3(256), 0, stream>>>(species, coords, lcf, out, ws);
}